// Round 2
// baseline (1157.346 us; speedup 1.0000x reference)
//
#include <hip/hip_runtime.h>

typedef __attribute__((ext_vector_type(8))) short short8;
typedef __attribute__((ext_vector_type(4))) float f32x4;
typedef unsigned short u16;

#define MFMA_BF16 __builtin_amdgcn_mfma_f32_16x16x32_bf16

__device__ __forceinline__ u16 f2bf(float f) {
    unsigned int u = __builtin_bit_cast(unsigned int, f);
    u = (u + 0x7FFFu + ((u >> 16) & 1u)) >> 16;
    return (u16)u;
}

__device__ __forceinline__ void gl_lds16(const void* g, void* l) {
    __builtin_amdgcn_global_load_lds(
        (const __attribute__((address_space(1))) unsigned int*)g,
        (__attribute__((address_space(3))) unsigned int*)l, 16, 0, 0);
}

constexpr int D = 768;
constexpr int S = 4096;

// ---------------- convert x fp32 -> bf16 row-major ----------------
__global__ __launch_bounds__(256)
void conv_x(const float* __restrict__ x, u16* __restrict__ xb) {
    const size_t i = ((size_t)blockIdx.x * 256 + threadIdx.x) * 4;
    const float4 v = *reinterpret_cast<const float4*>(x + i);
    ushort4 o;
    o.x = f2bf(v.x); o.y = f2bf(v.y); o.z = f2bf(v.z); o.w = f2bf(v.w);
    *reinterpret_cast<ushort4*>(xb + i) = o;
}

// ------------- convert W fp32 [k][n] -> bf16 transposed [n][k] -------------
__global__ __launch_bounds__(256)
void conv_wt(const float* __restrict__ Wq, const float* __restrict__ Wk,
             const float* __restrict__ Wv, u16* __restrict__ WT) {
    __shared__ float t[64][65];
    const int tid = threadIdx.x;
    const int k0 = blockIdx.x * 64, n0 = blockIdx.y * 64, z = blockIdx.z;
    const float* __restrict__ W = (z == 0) ? Wq : ((z == 1) ? Wk : Wv);
    #pragma unroll
    for (int i = 0; i < 4; ++i) {
        const int e = (i * 256 + tid) * 4;
        const int r = e >> 6, c = e & 63;
        const float4 v = *reinterpret_cast<const float4*>(W + (size_t)(k0 + r) * D + n0 + c);
        t[r][c] = v.x; t[r][c + 1] = v.y; t[r][c + 2] = v.z; t[r][c + 3] = v.w;
    }
    __syncthreads();
    u16* O = WT + (size_t)z * D * D;
    #pragma unroll
    for (int i = 0; i < 4; ++i) {
        const int e = (i * 256 + tid) * 4;
        const int n = e >> 6, kq = e & 63;
        ushort4 o;
        o.x = f2bf(t[kq + 0][n]); o.y = f2bf(t[kq + 1][n]);
        o.z = f2bf(t[kq + 2][n]); o.w = f2bf(t[kq + 3][n]);
        *reinterpret_cast<ushort4*>(O + (size_t)(n0 + n) * D + k0 + kq) = o;
    }
}

// ---------------- QKV GEMM: bf16 x bf16, global_load_lds, dbuf ----------------
__global__ __launch_bounds__(256)
void qkv_gemm(const u16* __restrict__ xb, const u16* __restrict__ WT,
              u16* __restrict__ qo, u16* __restrict__ ko, u16* __restrict__ vt)
{
    __shared__ u16 sA[2][128 * 32];
    __shared__ u16 sB[2][128 * 32];
    const int tid  = threadIdx.x;
    const int lane = tid & 63;
    const int w    = tid >> 6;
    const int wr   = w >> 1, wc = w & 1;
    const int bm   = blockIdx.x * 128;
    const int bn   = blockIdx.y * 128;
    const int z    = blockIdx.z;
    const u16* __restrict__ A = xb;
    const u16* __restrict__ B = WT + (size_t)z * D * D;

    f32x4 acc[4][4] = {};

    auto stage = [&](int buf, int kc) {
        #pragma unroll
        for (int c = 0; c < 2; ++c) {
            const int e   = (c * 256 + tid) * 8;
            const int row = e >> 5, col = e & 31;
            gl_lds16(A + (size_t)(bm + row) * D + kc * 32 + col, &sA[buf][e]);
            gl_lds16(B + (size_t)(bn + row) * D + kc * 32 + col, &sB[buf][e]);
        }
    };

    stage(0, 0);
    __syncthreads();
    int cur = 0;
    for (int kc = 0; kc < 24; ++kc) {
        if (kc < 23) stage(cur ^ 1, kc + 1);
        short8 af[4], bf4[4];
        #pragma unroll
        for (int fr = 0; fr < 4; ++fr)
            af[fr] = *reinterpret_cast<const short8*>(&sA[cur][(wr * 64 + fr * 16 + (lane & 15)) * 32 + (lane >> 4) * 8]);
        #pragma unroll
        for (int fc = 0; fc < 4; ++fc)
            bf4[fc] = *reinterpret_cast<const short8*>(&sB[cur][(wc * 64 + fc * 16 + (lane & 15)) * 32 + (lane >> 4) * 8]);
        #pragma unroll
        for (int fr = 0; fr < 4; ++fr)
            #pragma unroll
            for (int fc = 0; fc < 4; ++fc)
                acc[fr][fc] = MFMA_BF16(af[fr], bf4[fc], acc[fr][fc], 0, 0, 0);
        __syncthreads();
        cur ^= 1;
    }

    #pragma unroll
    for (int fr = 0; fr < 4; ++fr) {
        #pragma unroll
        for (int fc = 0; fc < 4; ++fc) {
            #pragma unroll
            for (int r = 0; r < 4; ++r) {
                const int m = bm + wr * 64 + fr * 16 + (lane >> 4) * 4 + r;
                const int n = bn + wc * 64 + fc * 16 + (lane & 15);
                const u16 hv = f2bf(acc[fr][fc][r]);
                if (z == 0)      qo[(size_t)m * D + n] = hv;
                else if (z == 1) ko[(size_t)m * D + n] = hv;
                else {
                    const int bb = m >> 12;
                    const int s  = m & (S - 1);
                    vt[((size_t)bb * D + n) * S + s] = hv;
                }
            }
        }
    }
}

// ---------------- Flash attention v2 ----------------
// QBLK=32, KBLK=64, 8 waves. Q in LDS (staged once). K,V B-frags direct from
// global (L2/L3-resident). 2 syncs per kt. LPT block order for causal balance.
__global__ __launch_bounds__(512)
void attn_fwd(const u16* __restrict__ Qg, const u16* __restrict__ Kg,
              const u16* __restrict__ Vt, float* __restrict__ out)
{
    __shared__ u16   sQ[32][784];    // pad: row stride 1568B -> 2-way only
    __shared__ float sS[32][68];
    __shared__ u16   sP[32][72];
    __shared__ float m_run[32], l_run[32], resc[32];

    const int tid  = threadIdx.x;
    const int lane = tid & 63;
    const int w    = tid >> 6;        // 0..7
    const int wr   = w >> 2;          // row-group 0..1 (16 rows)
    const int wc   = w & 3;           // key-group 0..3 (16 keys)
    const int qtile = 127 - blockIdx.x;   // LPT: biggest first
    const int b     = blockIdx.y;
    const int q0    = qtile * 32;
    const float scale = 0.03608439182435161f;  // 1/sqrt(768)

    // stage Q once: 32 x 768
    #pragma unroll
    for (int i = 0; i < 6; ++i) {
        const int c = i * 512 + tid;
        const int row = c / 96, col = (c % 96) * 8;
        *reinterpret_cast<short8*>(&sQ[row][col]) =
            *reinterpret_cast<const short8*>(Qg + ((size_t)b * S + q0 + row) * D + col);
    }
    if (tid < 32) { m_run[tid] = -1e30f; l_run[tid] = 0.0f; }
    __syncthreads();

    f32x4 acc[2][6] = {};
    const int kt_max = (qtile >> 1) + 1;
    const int vd = w * 96;           // wave's d-slice for PV
    const u16* __restrict__ Kbase = Kg + (size_t)b * S * D;

    const u16* qrow = &sQ[wr * 16 + (lane & 15)][(lane >> 4) * 8];

    for (int kt = 0; kt < kt_max; ++kt) {
        const int kb = kt * 64;
        // ---- QK^T: A from LDS Q, B direct from global K ----
        f32x4 qk0 = {}, qk1 = {};
        const u16* kp = Kbase + (size_t)(kb + wc * 16 + (lane & 15)) * D + (lane >> 4) * 8;
        #pragma unroll
        for (int kc = 0; kc < 24; kc += 2) {
            const short8 a0 = *reinterpret_cast<const short8*>(qrow + kc * 32);
            const short8 b0 = *reinterpret_cast<const short8*>(kp + kc * 32);
            qk0 = MFMA_BF16(a0, b0, qk0, 0, 0, 0);
            const short8 a1 = *reinterpret_cast<const short8*>(qrow + kc * 32 + 32);
            const short8 b1 = *reinterpret_cast<const short8*>(kp + kc * 32 + 32);
            qk1 = MFMA_BF16(a1, b1, qk1, 0, 0, 0);
        }
        const bool last = (kt == kt_max - 1);
        #pragma unroll
        for (int r = 0; r < 4; ++r) {
            float sv = qk0[r] + qk1[r];
            if (last) {
                const int grow = q0 + wr * 16 + (lane >> 4) * 4 + r;
                const int gcol = kb + wc * 16 + (lane & 15);
                if (gcol > grow) sv = -1e30f;
            }
            sS[wr * 16 + (lane >> 4) * 4 + r][wc * 16 + (lane & 15)] = sv;
        }
        __syncthreads();

        // ---- online softmax: 16 threads per row, 4 cols each ----
        {
            const int row = tid >> 4, sub = tid & 15;
            float tv[4];
            float mx = -1e30f;
            #pragma unroll
            for (int i = 0; i < 4; ++i) {
                tv[i] = sS[row][sub * 4 + i] * scale;
                mx = fmaxf(mx, tv[i]);
            }
            mx = fmaxf(mx, __shfl_xor(mx, 1));
            mx = fmaxf(mx, __shfl_xor(mx, 2));
            mx = fmaxf(mx, __shfl_xor(mx, 4));
            mx = fmaxf(mx, __shfl_xor(mx, 8));
            const float mold = m_run[row];
            const float mnew = fmaxf(mold, mx);
            const float sc   = __expf(mold - mnew);
            float ls = 0.0f;
            ushort4 pk;
            {
                const float p0 = __expf(tv[0] - mnew); ls += p0; pk.x = f2bf(p0);
                const float p1 = __expf(tv[1] - mnew); ls += p1; pk.y = f2bf(p1);
                const float p2 = __expf(tv[2] - mnew); ls += p2; pk.z = f2bf(p2);
                const float p3 = __expf(tv[3] - mnew); ls += p3; pk.w = f2bf(p3);
            }
            *reinterpret_cast<ushort4*>(&sP[row][sub * 4]) = pk;
            ls += __shfl_xor(ls, 1);
            ls += __shfl_xor(ls, 2);
            ls += __shfl_xor(ls, 4);
            ls += __shfl_xor(ls, 8);
            if (sub == 0) {
                l_run[row] = l_run[row] * sc + ls;
                m_run[row] = mnew;
                resc[row]  = sc;
            }
        }
        __syncthreads();

        // ---- PV: rescale acc, then P @ V^T-slice (V direct from global) ----
        #pragma unroll
        for (int fr = 0; fr < 2; ++fr)
            #pragma unroll
            for (int r = 0; r < 4; ++r) {
                const float scr = resc[fr * 16 + (lane >> 4) * 4 + r];
                #pragma unroll
                for (int fc = 0; fc < 6; ++fc) acc[fr][fc][r] *= scr;
            }
        #pragma unroll
        for (int ks = 0; ks < 2; ++ks) {
            const short8 a0 = *reinterpret_cast<const short8*>(&sP[(lane & 15)][ks * 32 + (lane >> 4) * 8]);
            const short8 a1 = *reinterpret_cast<const short8*>(&sP[16 + (lane & 15)][ks * 32 + (lane >> 4) * 8]);
            #pragma unroll
            for (int fc = 0; fc < 6; ++fc) {
                const short8 bv = *reinterpret_cast<const short8*>(
                    Vt + ((size_t)b * D + vd + fc * 16 + (lane & 15)) * S + kb + ks * 32 + (lane >> 4) * 8);
                acc[0][fc] = MFMA_BF16(a0, bv, acc[0][fc], 0, 0, 0);
                acc[1][fc] = MFMA_BF16(a1, bv, acc[1][fc], 0, 0, 0);
            }
        }
    }

    // ---- epilogue ----
    #pragma unroll
    for (int fr = 0; fr < 2; ++fr) {
        #pragma unroll
        for (int r = 0; r < 4; ++r) {
            const int row = fr * 16 + (lane >> 4) * 4 + r;
            const float inv = 1.0f / l_run[row];
            float* op = out + ((size_t)b * S + q0 + row) * D + vd;
            #pragma unroll
            for (int fc = 0; fc < 6; ++fc)
                op[fc * 16 + (lane & 15)] = acc[fr][fc][r] * inv;
        }
    }
}

extern "C" void kernel_launch(void* const* d_in, const int* in_sizes, int n_in,
                              void* d_out, int out_size, void* d_ws, size_t ws_size,
                              hipStream_t stream) {
    const float* x  = (const float*)d_in[0];
    const float* Wq = (const float*)d_in[1];
    const float* Wk = (const float*)d_in[2];
    const float* Wv = (const float*)d_in[3];
    float* out = (float*)d_out;

    const size_t SD = (size_t)16384 * 768;    // 12.58M elems
    u16* q  = (u16*)d_ws;                     // 25.2 MB
    u16* k  = q  + SD;                        // 25.2 MB
    u16* vt = k  + SD;                        // 25.2 MB
    u16* xb = vt + SD;                        // 25.2 MB
    u16* WT = xb + SD;                        // 3.5 MB   (~104 MB total)
    (void)in_sizes; (void)n_in; (void)out_size; (void)ws_size;

    conv_x  <<<12288, 256, 0, stream>>>(x, xb);
    conv_wt <<<dim3(12, 12, 3), 256, 0, stream>>>(Wq, Wk, Wv, WT);
    qkv_gemm<<<dim3(128, 6, 3), 256, 0, stream>>>(xb, WT, q, k, vt);
    attn_fwd<<<dim3(128, 4), 512, 0, stream>>>(q, k, vt, out);
}

// Round 3
// 363.740 us; speedup vs baseline: 3.1818x; 3.1818x over previous
//
#include <hip/hip_runtime.h>

typedef __attribute__((ext_vector_type(8))) short short8;
typedef __attribute__((ext_vector_type(4))) float f32x4;
typedef unsigned short u16;

#define MFMA_BF16 __builtin_amdgcn_mfma_f32_16x16x32_bf16

__device__ __forceinline__ u16 f2bf(float f) {
    unsigned int u = __builtin_bit_cast(unsigned int, f);
    u = (u + 0x7FFFu + ((u >> 16) & 1u)) >> 16;
    return (u16)u;
}
__device__ __forceinline__ float h2f(u16 h) {
    return (float)__builtin_bit_cast(_Float16, h);
}
__device__ __forceinline__ u16 f2h(float f) {
    return __builtin_bit_cast(u16, (_Float16)f);
}

__device__ __forceinline__ void gl_lds16(const void* g, void* l) {
    __builtin_amdgcn_global_load_lds(
        (const __attribute__((address_space(1))) unsigned int*)g,
        (__attribute__((address_space(3))) unsigned int*)l, 16, 0, 0);
}

constexpr int D = 768;
constexpr int S = 4096;
constexpr float SCALE = 0.03608439182435161f;   // 1/sqrt(768)

// decode lower-tri tile index t -> (i,j), j<=i, t = i(i+1)/2 + j
__device__ __forceinline__ void tri_decode(int t, int& i, int& j) {
    i = (int)((sqrtf(8.0f * t + 1.0f) - 1.0f) * 0.5f);
    while ((i + 1) * (i + 2) / 2 <= t) ++i;
    while (i * (i + 1) / 2 > t) --i;
    j = t - i * (i + 1) / 2;
}

// ---------------- convert x fp32 -> bf16 row-major ----------------
__global__ __launch_bounds__(256)
void conv_x(const float* __restrict__ x, u16* __restrict__ xb) {
    const size_t i = ((size_t)blockIdx.x * 256 + threadIdx.x) * 4;
    const float4 v = *reinterpret_cast<const float4*>(x + i);
    ushort4 o;
    o.x = f2bf(v.x); o.y = f2bf(v.y); o.z = f2bf(v.z); o.w = f2bf(v.w);
    *reinterpret_cast<ushort4*>(xb + i) = o;
}

// ------------- convert W fp32 [k][n] -> bf16 transposed [n][k] -------------
__global__ __launch_bounds__(256)
void conv_wt(const float* __restrict__ Wq, const float* __restrict__ Wk,
             const float* __restrict__ Wv, u16* __restrict__ WT) {
    __shared__ float t[64][65];
    const int tid = threadIdx.x;
    const int k0 = blockIdx.x * 64, n0 = blockIdx.y * 64, z = blockIdx.z;
    const float* __restrict__ W = (z == 0) ? Wq : ((z == 1) ? Wk : Wv);
    #pragma unroll
    for (int i = 0; i < 4; ++i) {
        const int e = (i * 256 + tid) * 4;
        const int r = e >> 6, c = e & 63;
        const float4 v = *reinterpret_cast<const float4*>(W + (size_t)(k0 + r) * D + n0 + c);
        t[r][c] = v.x; t[r][c + 1] = v.y; t[r][c + 2] = v.z; t[r][c + 3] = v.w;
    }
    __syncthreads();
    u16* O = WT + (size_t)z * D * D;
    #pragma unroll
    for (int i = 0; i < 4; ++i) {
        const int e = (i * 256 + tid) * 4;
        const int n = e >> 6, kq = e & 63;
        ushort4 o;
        o.x = f2bf(t[kq + 0][n]); o.y = f2bf(t[kq + 1][n]);
        o.z = f2bf(t[kq + 2][n]); o.w = f2bf(t[kq + 3][n]);
        *reinterpret_cast<ushort4*>(O + (size_t)(n0 + n) * D + k0 + kq) = o;
    }
}

// ---------------- QKV GEMM: bf16 x bf16, global_load_lds, dbuf ----------------
__global__ __launch_bounds__(256)
void qkv_gemm(const u16* __restrict__ xb, const u16* __restrict__ WT,
              u16* __restrict__ qo, u16* __restrict__ ko, u16* __restrict__ vt)
{
    __shared__ u16 sA[2][128 * 32];
    __shared__ u16 sB[2][128 * 32];
    const int tid  = threadIdx.x;
    const int lane = tid & 63;
    const int w    = tid >> 6;
    const int wr   = w >> 1, wc = w & 1;
    const int bm   = blockIdx.x * 128;
    const int bn   = blockIdx.y * 128;
    const int z    = blockIdx.z;
    const u16* __restrict__ A = xb;
    const u16* __restrict__ B = WT + (size_t)z * D * D;

    f32x4 acc[4][4] = {};

    auto stage = [&](int buf, int kc) {
        #pragma unroll
        for (int c = 0; c < 2; ++c) {
            const int e   = (c * 256 + tid) * 8;
            const int row = e >> 5, col = e & 31;
            gl_lds16(A + (size_t)(bm + row) * D + kc * 32 + col, &sA[buf][e]);
            gl_lds16(B + (size_t)(bn + row) * D + kc * 32 + col, &sB[buf][e]);
        }
    };

    stage(0, 0);
    __syncthreads();
    int cur = 0;
    for (int kc = 0; kc < 24; ++kc) {
        if (kc < 23) stage(cur ^ 1, kc + 1);
        short8 af[4], bf4[4];
        #pragma unroll
        for (int fr = 0; fr < 4; ++fr)
            af[fr] = *reinterpret_cast<const short8*>(&sA[cur][(wr * 64 + fr * 16 + (lane & 15)) * 32 + (lane >> 4) * 8]);
        #pragma unroll
        for (int fc = 0; fc < 4; ++fc)
            bf4[fc] = *reinterpret_cast<const short8*>(&sB[cur][(wc * 64 + fc * 16 + (lane & 15)) * 32 + (lane >> 4) * 8]);
        #pragma unroll
        for (int fr = 0; fr < 4; ++fr)
            #pragma unroll
            for (int fc = 0; fc < 4; ++fc)
                acc[fr][fc] = MFMA_BF16(af[fr], bf4[fc], acc[fr][fc], 0, 0, 0);
        __syncthreads();
        cur ^= 1;
    }

    #pragma unroll
    for (int fr = 0; fr < 4; ++fr) {
        #pragma unroll
        for (int fc = 0; fc < 4; ++fc) {
            #pragma unroll
            for (int r = 0; r < 4; ++r) {
                const int m = bm + wr * 64 + fr * 16 + (lane >> 4) * 4 + r;
                const int n = bn + wc * 64 + fc * 16 + (lane & 15);
                const u16 hv = f2bf(acc[fr][fc][r]);
                if (z == 0)      qo[(size_t)m * D + n] = hv;
                else if (z == 1) ko[(size_t)m * D + n] = hv;
                else {
                    const int bb = m >> 12;
                    const int s  = m & (S - 1);
                    vt[((size_t)bb * D + n) * S + s] = hv;
                }
            }
        }
    }
}

// ---------------- QK^T: causal 128x128 tiles -> packed fp16 ----------------
__global__ __launch_bounds__(256)
void qkt_gemm(const u16* __restrict__ Qg, const u16* __restrict__ Kg,
              u16* __restrict__ Sp)
{
    __shared__ u16 sA[2][128 * 32];
    __shared__ u16 sB[2][128 * 32];
    const int tid  = threadIdx.x;
    const int lane = tid & 63;
    const int w    = tid >> 6;
    const int wr   = w >> 1, wc = w & 1;
    int ti, tj;
    tri_decode(blockIdx.x, ti, tj);
    const int b = blockIdx.y;
    const u16* __restrict__ A = Qg + ((size_t)b * S + ti * 128) * D;
    const u16* __restrict__ B = Kg + ((size_t)b * S + tj * 128) * D;

    f32x4 acc[4][4] = {};

    auto stage = [&](int buf, int kc) {
        #pragma unroll
        for (int c = 0; c < 2; ++c) {
            const int e   = (c * 256 + tid) * 8;
            const int row = e >> 5, col = e & 31;
            gl_lds16(A + (size_t)row * D + kc * 32 + col, &sA[buf][e]);
            gl_lds16(B + (size_t)row * D + kc * 32 + col, &sB[buf][e]);
        }
    };

    stage(0, 0);
    __syncthreads();
    int cur = 0;
    for (int kc = 0; kc < 24; ++kc) {
        if (kc < 23) stage(cur ^ 1, kc + 1);
        short8 af[4], bf4[4];
        #pragma unroll
        for (int fr = 0; fr < 4; ++fr)
            af[fr] = *reinterpret_cast<const short8*>(&sA[cur][(wr * 64 + fr * 16 + (lane & 15)) * 32 + (lane >> 4) * 8]);
        #pragma unroll
        for (int fc = 0; fc < 4; ++fc)
            bf4[fc] = *reinterpret_cast<const short8*>(&sB[cur][(wc * 64 + fc * 16 + (lane & 15)) * 32 + (lane >> 4) * 8]);
        #pragma unroll
        for (int fr = 0; fr < 4; ++fr)
            #pragma unroll
            for (int fc = 0; fc < 4; ++fc)
                acc[fr][fc] = MFMA_BF16(af[fr], bf4[fc], acc[fr][fc], 0, 0, 0);
        __syncthreads();
        cur ^= 1;
    }

    u16* outT = Sp + ((size_t)b * 528 + blockIdx.x) * 16384;
    #pragma unroll
    for (int fr = 0; fr < 4; ++fr)
        #pragma unroll
        for (int fc = 0; fc < 4; ++fc)
            #pragma unroll
            for (int r = 0; r < 4; ++r) {
                const int m = wr * 64 + fr * 16 + (lane >> 4) * 4 + r;
                const int n = wc * 64 + fc * 16 + (lane & 15);
                outT[m * 128 + n] = f2h(acc[fr][fc][r]);
            }
}

// ------------- reduce1: per-tile per-row (max, sumexp) partials -------------
__global__ __launch_bounds__(256)
void reduce1(const u16* __restrict__ Sp, float* __restrict__ Mp, float* __restrict__ Lp)
{
    int ti, tj;
    tri_decode(blockIdx.x, ti, tj);
    const int b = blockIdx.y;
    const int r = threadIdx.x >> 1, h = threadIdx.x & 1;
    const u16* base = Sp + ((size_t)b * 528 + blockIdx.x) * 16384 + r * 128 + h * 64;
    const int row_g = ti * 128 + r;
    const int col0  = tj * 128 + h * 64;
    const bool diag = (ti == tj);

    float m = -1e30f, l = 0.0f;
    #pragma unroll
    for (int c8 = 0; c8 < 8; ++c8) {
        short8 v = *reinterpret_cast<const short8*>(base + c8 * 8);
        float f[8];
        bool  ok[8];
        #pragma unroll
        for (int e = 0; e < 8; ++e) {
            f[e]  = h2f((u16)v[e]);
            ok[e] = (!diag) || (col0 + c8 * 8 + e <= row_g);
            if (!ok[e]) f[e] = -1e30f;
        }
        float mc = f[0];
        #pragma unroll
        for (int e = 1; e < 8; ++e) mc = fmaxf(mc, f[e]);
        const float mn = fmaxf(m, mc);
        l *= __expf(SCALE * (m - mn));
        #pragma unroll
        for (int e = 0; e < 8; ++e)
            l += ok[e] ? __expf(SCALE * (f[e] - mn)) : 0.0f;
        m = mn;
    }
    // merge the two half-row threads
    {
        const float mo = __shfl_xor(m, 1);
        const float lo = __shfl_xor(l, 1);
        const float mn = fmaxf(m, mo);
        l = l * __expf(SCALE * (m - mn)) + lo * __expf(SCALE * (mo - mn));
        m = mn;
    }
    if (h == 0) {
        Mp[((size_t)b * 32 + tj) * 4096 + row_g] = m;
        Lp[((size_t)b * 32 + tj) * 4096 + row_g] = l;
    }
}

// ------------- reduce2: combine partials over tile-col -> sm, 1/l -------------
__global__ __launch_bounds__(256)
void reduce2(const float* __restrict__ Mp, const float* __restrict__ Lp,
             float* __restrict__ SM, float* __restrict__ Li)
{
    const int row = blockIdx.x * 256 + threadIdx.x;   // 0..16383
    const int b = row >> 12, r = row & 4095, imax = r >> 7;
    float m = -1e30f, l = 0.0f;
    for (int j = 0; j <= imax; ++j) {
        const float mp = Mp[((size_t)b * 32 + j) * 4096 + r];
        const float lp = Lp[((size_t)b * 32 + j) * 4096 + r];
        const float mn = fmaxf(m, mp);
        l = l * __expf(SCALE * (m - mn)) + lp * __expf(SCALE * (mp - mn));
        m = mn;
    }
    SM[row] = SCALE * m;
    Li[row] = 1.0f / l;
}

// ---------------- PV: P = exp(scale*s - sm), O = (P @ V^T) * Li ----------------
// 512 threads (8 waves, 2q x 4d), item = (b, q-tile i, d-quarter dq).
// WG k runs items {k, 511-k}: cost(k-item)+cost(pair) = const -> balanced.
__global__ __launch_bounds__(512)
void pv_gemm(const u16* __restrict__ Sp, const u16* __restrict__ Vt,
             const float* __restrict__ SM, const float* __restrict__ Li,
             float* __restrict__ out)
{
    __shared__ u16 sV[2][192 * 64];      // [d][key] swizzled
    __shared__ u16 sP[2][128][72];       // [q][key] padded
    const int tid  = threadIdx.x;
    const int lane = tid & 63;
    const int w    = tid >> 6;
    const int wq   = w >> 2;             // 0..1 (64 q-rows)
    const int wd   = w & 3;              // 0..3 (48 d-cols)

    #pragma unroll
    for (int it = 0; it < 2; ++it) {
        const int e  = (it == 0) ? (int)blockIdx.x : (511 - (int)blockIdx.x);
        const int i  = 31 - (e >> 4);
        const int b  = (e >> 2) & 3;
        const int dq = e & 3;
        const int q0 = i * 128, d0 = dq * 192;
        const int nkt = 2 * i + 2;
        const u16* __restrict__ Spb = Sp + ((size_t)b * 528 + (size_t)i * (i + 1) / 2) * 16384;
        const u16* __restrict__ vtb = Vt + ((size_t)b * D + d0) * S;

        const int sr  = tid >> 2;        // q-row this thread stages
        const int sc4 = tid & 3;         // 16-key chunk
        const float smrow = SM[b * 4096 + q0 + sr];

        f32x4 acc[4][3] = {};

        auto stage_v = [&](int buf, int kt) {
            #pragma unroll
            for (int n = 0; n < 3; ++n) {
                const int f16 = n * 512 + tid;          // 16B chunk 0..1535
                const int row = f16 >> 3;               // d-row
                const int csw = (f16 & 7) ^ (row & 7);  // pre-swizzled source chunk
                gl_lds16(vtb + (size_t)row * S + kt * 64 + csw * 8,
                         &sV[buf][(size_t)f16 * 8]);
            }
        };
        auto stage_p = [&](int buf, int kt) {
            const u16* sb = Spb + (size_t)(kt >> 1) * 16384 + sr * 128 + (kt & 1) * 64 + sc4 * 16;
            const short8 s0 = *reinterpret_cast<const short8*>(sb);
            const short8 s1 = *reinterpret_cast<const short8*>(sb + 8);
            const int rowg = q0 + sr;
            short8 p0, p1;
            #pragma unroll
            for (int ee = 0; ee < 8; ++ee) {
                const int cg = kt * 64 + sc4 * 16 + ee;
                const float f0 = (cg <= rowg) ? __expf(h2f((u16)s0[ee]) * SCALE - smrow) : 0.0f;
                p0[ee] = (short)f2bf(f0);
                const int cg1 = cg + 8;
                const float f1 = (cg1 <= rowg) ? __expf(h2f((u16)s1[ee]) * SCALE - smrow) : 0.0f;
                p1[ee] = (short)f2bf(f1);
            }
            *reinterpret_cast<short8*>(&sP[buf][sr][sc4 * 16])     = p0;
            *reinterpret_cast<short8*>(&sP[buf][sr][sc4 * 16 + 8]) = p1;
        };

        stage_v(0, 0);
        stage_p(0, 0);
        __syncthreads();

        int cur = 0;
        for (int kt = 0; kt < nkt; ++kt) {
            if (kt + 1 < nkt) stage_v(cur ^ 1, kt + 1);
            #pragma unroll
            for (int ks = 0; ks < 2; ++ks) {
                short8 a[4];
                #pragma unroll
                for (int fr = 0; fr < 4; ++fr)
                    a[fr] = *reinterpret_cast<const short8*>(
                        &sP[cur][wq * 64 + fr * 16 + (lane & 15)][ks * 32 + (lane >> 4) * 8]);
                #pragma unroll
                for (int fc = 0; fc < 3; ++fc) {
                    const int dr = wd * 48 + fc * 16 + (lane & 15);
                    const int cb = (ks * 64 + (lane >> 4) * 16) ^ ((dr & 7) << 4);
                    const short8 bv = *reinterpret_cast<const short8*>(
                        &sV[cur][dr * 64 + (cb >> 1)]);
                    #pragma unroll
                    for (int fr = 0; fr < 4; ++fr)
                        acc[fr][fc] = MFMA_BF16(a[fr], bv, acc[fr][fc], 0, 0, 0);
                }
            }
            if (kt + 1 < nkt) stage_p(cur ^ 1, kt + 1);
            __syncthreads();
            cur ^= 1;
        }

        // epilogue
        #pragma unroll
        for (int fr = 0; fr < 4; ++fr)
            #pragma unroll
            for (int rr = 0; rr < 4; ++rr) {
                const int row = q0 + wq * 64 + fr * 16 + (lane >> 4) * 4 + rr;
                const float linv = Li[b * 4096 + row];
                #pragma unroll
                for (int fc = 0; fc < 3; ++fc) {
                    const int col = d0 + wd * 48 + fc * 16 + (lane & 15);
                    out[((size_t)b * S + row) * D + col] = acc[fr][fc][rr] * linv;
                }
            }
        __syncthreads();   // protect LDS before next item's prologue
    }
}

extern "C" void kernel_launch(void* const* d_in, const int* in_sizes, int n_in,
                              void* d_out, int out_size, void* d_ws, size_t ws_size,
                              hipStream_t stream) {
    const float* x  = (const float*)d_in[0];
    const float* Wq = (const float*)d_in[1];
    const float* Wk = (const float*)d_in[2];
    const float* Wv = (const float*)d_in[3];
    float* out = (float*)d_out;

    const size_t SD = (size_t)16384 * 768;
    u16* q  = (u16*)d_ws;
    u16* k  = q  + SD;
    u16* vt = k  + SD;
    u16* xb = vt + SD;
    u16* WT = xb + SD;                         // 3*768*768 = 1,769,472
    u16* Sp = WT + (size_t)3 * 768 * 768;      // 4*528*16384 = 34,603,008
    float* Mp = (float*)(Sp + (size_t)4 * 528 * 16384);
    float* Lp = Mp + (size_t)4 * 32 * 4096;
    float* SM = Lp + (size_t)4 * 32 * 4096;
    float* Li = SM + 16384;
    (void)in_sizes; (void)n_in; (void)out_size; (void)ws_size;

    conv_x  <<<12288, 256, 0, stream>>>(x, xb);
    conv_wt <<<dim3(12, 12, 3), 256, 0, stream>>>(Wq, Wk, Wv, WT);
    qkv_gemm<<<dim3(128, 6, 3), 256, 0, stream>>>(xb, WT, q, k, vt);
    qkt_gemm<<<dim3(528, 4), 256, 0, stream>>>(q, k, Sp);
    reduce1 <<<dim3(528, 4), 256, 0, stream>>>(Sp, Mp, Lp);
    reduce2 <<<64, 256, 0, stream>>>(Mp, Lp, SM, Li);
    pv_gemm <<<256, 512, 0, stream>>>(Sp, vt, SM, Li, out);
}

// Round 4
// 308.518 us; speedup vs baseline: 3.7513x; 1.1790x over previous
//
#include <hip/hip_runtime.h>

typedef __attribute__((ext_vector_type(8))) short short8;
typedef __attribute__((ext_vector_type(4))) float f32x4;
typedef unsigned short u16;

#define MFMA_BF16 __builtin_amdgcn_mfma_f32_16x16x32_bf16

__device__ __forceinline__ u16 f2bf(float f) {
    unsigned int u = __builtin_bit_cast(unsigned int, f);
    u = (u + 0x7FFFu + ((u >> 16) & 1u)) >> 16;
    return (u16)u;
}

__device__ __forceinline__ void gl_lds16(const void* g, void* l) {
    __builtin_amdgcn_global_load_lds(
        (const __attribute__((address_space(1))) unsigned int*)g,
        (__attribute__((address_space(3))) unsigned int*)l, 16, 0, 0);
}

constexpr int D = 768;
constexpr int S = 4096;
constexpr float SCALE = 0.03608439182435161f;   // 1/sqrt(768)

// decode lower-tri tile index t -> (i,j), j<=i, t = i(i+1)/2 + j
__device__ __forceinline__ void tri_decode(int t, int& i, int& j) {
    i = (int)((sqrtf(8.0f * t + 1.0f) - 1.0f) * 0.5f);
    while ((i + 1) * (i + 2) / 2 <= t) ++i;
    while (i * (i + 1) / 2 > t) --i;
    j = t - i * (i + 1) / 2;
}

// ---------------- convert x fp32 -> bf16 row-major ----------------
__global__ __launch_bounds__(256)
void conv_x(const float* __restrict__ x, u16* __restrict__ xb) {
    const size_t i = ((size_t)blockIdx.x * 256 + threadIdx.x) * 4;
    const float4 v = *reinterpret_cast<const float4*>(x + i);
    ushort4 o;
    o.x = f2bf(v.x); o.y = f2bf(v.y); o.z = f2bf(v.z); o.w = f2bf(v.w);
    *reinterpret_cast<ushort4*>(xb + i) = o;
}

// ------------- convert W fp32 [k][n] -> bf16 transposed [n][k] -------------
__global__ __launch_bounds__(256)
void conv_wt(const float* __restrict__ Wq, const float* __restrict__ Wk,
             const float* __restrict__ Wv, u16* __restrict__ WT) {
    __shared__ float t[64][65];
    const int tid = threadIdx.x;
    const int k0 = blockIdx.x * 64, n0 = blockIdx.y * 64, z = blockIdx.z;
    const float* __restrict__ W = (z == 0) ? Wq : ((z == 1) ? Wk : Wv);
    #pragma unroll
    for (int i = 0; i < 4; ++i) {
        const int e = (i * 256 + tid) * 4;
        const int r = e >> 6, c = e & 63;
        const float4 v = *reinterpret_cast<const float4*>(W + (size_t)(k0 + r) * D + n0 + c);
        t[r][c] = v.x; t[r][c + 1] = v.y; t[r][c + 2] = v.z; t[r][c + 3] = v.w;
    }
    __syncthreads();
    u16* O = WT + (size_t)z * D * D;
    #pragma unroll
    for (int i = 0; i < 4; ++i) {
        const int e = (i * 256 + tid) * 4;
        const int n = e >> 6, kq = e & 63;
        ushort4 o;
        o.x = f2bf(t[kq + 0][n]); o.y = f2bf(t[kq + 1][n]);
        o.z = f2bf(t[kq + 2][n]); o.w = f2bf(t[kq + 3][n]);
        *reinterpret_cast<ushort4*>(O + (size_t)(n0 + n) * D + k0 + kq) = o;
    }
}

// ---------------- QKV GEMM: bf16 x bf16, global_load_lds, dbuf ----------------
__global__ __launch_bounds__(256)
void qkv_gemm(const u16* __restrict__ xb, const u16* __restrict__ WT,
              u16* __restrict__ qo, u16* __restrict__ ko, u16* __restrict__ vt)
{
    __shared__ u16 sA[2][128 * 32];
    __shared__ u16 sB[2][128 * 32];
    const int tid  = threadIdx.x;
    const int lane = tid & 63;
    const int w    = tid >> 6;
    const int wr   = w >> 1, wc = w & 1;
    const int bm   = blockIdx.x * 128;
    const int bn   = blockIdx.y * 128;
    const int z    = blockIdx.z;
    const u16* __restrict__ A = xb;
    const u16* __restrict__ B = WT + (size_t)z * D * D;

    f32x4 acc[4][4] = {};

    auto stage = [&](int buf, int kc) {
        #pragma unroll
        for (int c = 0; c < 2; ++c) {
            const int e   = (c * 256 + tid) * 8;
            const int row = e >> 5, col = e & 31;
            gl_lds16(A + (size_t)(bm + row) * D + kc * 32 + col, &sA[buf][e]);
            gl_lds16(B + (size_t)(bn + row) * D + kc * 32 + col, &sB[buf][e]);
        }
    };

    stage(0, 0);
    __syncthreads();
    int cur = 0;
    for (int kc = 0; kc < 24; ++kc) {
        if (kc < 23) stage(cur ^ 1, kc + 1);
        short8 af[4], bf4[4];
        #pragma unroll
        for (int fr = 0; fr < 4; ++fr)
            af[fr] = *reinterpret_cast<const short8*>(&sA[cur][(wr * 64 + fr * 16 + (lane & 15)) * 32 + (lane >> 4) * 8]);
        #pragma unroll
        for (int fc = 0; fc < 4; ++fc)
            bf4[fc] = *reinterpret_cast<const short8*>(&sB[cur][(wc * 64 + fc * 16 + (lane & 15)) * 32 + (lane >> 4) * 8]);
        #pragma unroll
        for (int fr = 0; fr < 4; ++fr)
            #pragma unroll
            for (int fc = 0; fc < 4; ++fc)
                acc[fr][fc] = MFMA_BF16(af[fr], bf4[fc], acc[fr][fc], 0, 0, 0);
        __syncthreads();
        cur ^= 1;
    }

    #pragma unroll
    for (int fr = 0; fr < 4; ++fr) {
        #pragma unroll
        for (int fc = 0; fc < 4; ++fc) {
            #pragma unroll
            for (int r = 0; r < 4; ++r) {
                const int m = bm + wr * 64 + fr * 16 + (lane >> 4) * 4 + r;
                const int n = bn + wc * 64 + fc * 16 + (lane & 15);
                const u16 hv = f2bf(acc[fr][fc][r]);
                if (z == 0)      qo[(size_t)m * D + n] = hv;
                else if (z == 1) ko[(size_t)m * D + n] = hv;
                else {
                    const int bb = m >> 12;
                    const int s  = m & (S - 1);
                    vt[((size_t)bb * D + n) * S + s] = hv;
                }
            }
        }
    }
}

// ------- QK^T: causal 128x128 tiles -> P = exp(scale*s - 10) bf16 + row-sum partials -------
__global__ __launch_bounds__(256)
void qkt_gemm(const u16* __restrict__ Qg, const u16* __restrict__ Kg,
              u16* __restrict__ Pp, float* __restrict__ Lp)
{
    __shared__ u16 sA[2][128 * 32];
    __shared__ u16 sB[2][128 * 32];
    const int tid  = threadIdx.x;
    const int lane = tid & 63;
    const int w    = tid >> 6;
    const int wr   = w >> 1, wc = w & 1;
    int ti, tj;
    tri_decode(blockIdx.x, ti, tj);
    const int b = blockIdx.y;
    const u16* __restrict__ A = Qg + ((size_t)b * S + ti * 128) * D;
    const u16* __restrict__ B = Kg + ((size_t)b * S + tj * 128) * D;

    f32x4 acc[4][4] = {};

    auto stage = [&](int buf, int kc) {
        #pragma unroll
        for (int c = 0; c < 2; ++c) {
            const int e   = (c * 256 + tid) * 8;
            const int row = e >> 5, col = e & 31;
            gl_lds16(A + (size_t)row * D + kc * 32 + col, &sA[buf][e]);
            gl_lds16(B + (size_t)row * D + kc * 32 + col, &sB[buf][e]);
        }
    };

    stage(0, 0);
    __syncthreads();
    int cur = 0;
    for (int kc = 0; kc < 24; ++kc) {
        if (kc < 23) stage(cur ^ 1, kc + 1);
        short8 af[4], bf4[4];
        #pragma unroll
        for (int fr = 0; fr < 4; ++fr)
            af[fr] = *reinterpret_cast<const short8*>(&sA[cur][(wr * 64 + fr * 16 + (lane & 15)) * 32 + (lane >> 4) * 8]);
        #pragma unroll
        for (int fc = 0; fc < 4; ++fc)
            bf4[fc] = *reinterpret_cast<const short8*>(&sB[cur][(wc * 64 + fc * 16 + (lane & 15)) * 32 + (lane >> 4) * 8]);
        #pragma unroll
        for (int fr = 0; fr < 4; ++fr)
            #pragma unroll
            for (int fc = 0; fc < 4; ++fc)
                acc[fr][fc] = MFMA_BF16(af[fr], bf4[fc], acc[fr][fc], 0, 0, 0);
        __syncthreads();
        cur ^= 1;
    }

    const bool diag = (ti == tj);
    u16* outT = Pp + ((size_t)b * 528 + blockIdx.x) * 16384;
    #pragma unroll
    for (int fr = 0; fr < 4; ++fr) {
        #pragma unroll
        for (int r = 0; r < 4; ++r) {
            const int m = wr * 64 + fr * 16 + (lane >> 4) * 4 + r;
            float rs = 0.0f;
            #pragma unroll
            for (int fc = 0; fc < 4; ++fc) {
                const int n = wc * 64 + fc * 16 + (lane & 15);
                float p = __expf(acc[fr][fc][r] * SCALE - 10.0f);
                if (diag && n > m) p = 0.0f;
                rs += p;
                outT[m * 128 + n] = f2bf(p);
            }
            rs += __shfl_xor(rs, 1);
            rs += __shfl_xor(rs, 2);
            rs += __shfl_xor(rs, 4);
            rs += __shfl_xor(rs, 8);
            if ((lane & 15) == 0)
                Lp[(((size_t)b * 32 + tj) * 2 + wc) * 4096 + ti * 128 + m] = rs;
        }
    }
}

// ------------- reduce_l: combine partials -> Li = 1/rowsum -------------
__global__ __launch_bounds__(256)
void reduce_l(const float* __restrict__ Lp, float* __restrict__ Li)
{
    const int row = blockIdx.x * 256 + threadIdx.x;   // 0..16383
    const int b = row >> 12, r = row & 4095, imax = r >> 7;
    float l = 0.0f;
    for (int j = 0; j <= imax; ++j) {
        l += Lp[(((size_t)b * 32 + j) * 2 + 0) * 4096 + r];
        l += Lp[(((size_t)b * 32 + j) * 2 + 1) * 4096 + r];
    }
    Li[row] = 1.0f / l;
}

// ---------------- PV: pure GEMM, O = (P @ V^T) * Li ----------------
// 512 WGs (8 waves each, 2q x 4d), item = (i, b, dq), LPT order (big i first).
// P and V both staged via global_load_lds with both-sides XOR swizzle.
__global__ __launch_bounds__(512)
void pv_gemm(const u16* __restrict__ Pp, const u16* __restrict__ Vt,
             const float* __restrict__ Li, float* __restrict__ out)
{
    __shared__ u16 sV[2][192 * 64];      // 48 KB
    __shared__ u16 sP[2][128 * 64];      // 32 KB  (total 80 KB -> 2 WG/CU)
    const int tid  = threadIdx.x;
    const int lane = tid & 63;
    const int w    = tid >> 6;
    const int wq   = w >> 2;             // 0..1 (64 q-rows)
    const int wd   = w & 3;              // 0..3 (48 d-cols)
    const int bid  = blockIdx.x;
    const int i    = 31 - (bid >> 4);    // LPT: biggest first
    const int b    = (bid >> 2) & 3;
    const int dq   = bid & 3;
    const int q0   = i * 128, d0 = dq * 192;
    const int nkt  = 2 * i + 2;
    const u16* __restrict__ Pt  = Pp + ((size_t)b * 528 + (size_t)i * (i + 1) / 2) * 16384;
    const u16* __restrict__ vtb = Vt + ((size_t)b * D + d0) * S;

    f32x4 acc[4][3] = {};

    auto stage_v = [&](int buf, int kt) {
        #pragma unroll
        for (int n = 0; n < 3; ++n) {
            const int ch  = n * 512 + tid;          // 16B chunk 0..1535
            const int row = ch >> 3;                // d-row 0..191
            const int csw = (ch & 7) ^ (row & 7);   // pre-swizzled source chunk
            gl_lds16(vtb + (size_t)row * S + kt * 64 + csw * 8, &sV[buf][ch * 8]);
        }
    };
    auto stage_p = [&](int buf, int kt) {
        const u16* base = Pt + (size_t)(kt >> 1) * 16384 + (kt & 1) * 64;
        #pragma unroll
        for (int n = 0; n < 2; ++n) {
            const int ch  = n * 512 + tid;          // 16B chunk 0..1023
            const int row = ch >> 3;                // q-row 0..127
            const int csw = (ch & 7) ^ (row & 7);
            gl_lds16(base + row * 128 + csw * 8, &sP[buf][ch * 8]);
        }
    };

    stage_v(0, 0); stage_p(0, 0);
    __syncthreads();
    int cur = 0;
    for (int kt = 0; kt < nkt; ++kt) {
        if (kt + 1 < nkt) { stage_v(cur ^ 1, kt + 1); stage_p(cur ^ 1, kt + 1); }
        #pragma unroll
        for (int ks = 0; ks < 2; ++ks) {
            short8 a[4];
            #pragma unroll
            for (int fr = 0; fr < 4; ++fr) {
                const int row = wq * 64 + fr * 16 + (lane & 15);
                const int cch = (ks * 4 + (lane >> 4)) ^ (row & 7);
                a[fr] = *reinterpret_cast<const short8*>(&sP[cur][row * 64 + cch * 8]);
            }
            #pragma unroll
            for (int fc = 0; fc < 3; ++fc) {
                const int dr  = wd * 48 + fc * 16 + (lane & 15);
                const int vch = (ks * 4 + (lane >> 4)) ^ (dr & 7);
                const short8 bv = *reinterpret_cast<const short8*>(&sV[cur][dr * 64 + vch * 8]);
                #pragma unroll
                for (int fr = 0; fr < 4; ++fr)
                    acc[fr][fc] = MFMA_BF16(a[fr], bv, acc[fr][fc], 0, 0, 0);
            }
        }
        __syncthreads();
        cur ^= 1;
    }

    #pragma unroll
    for (int fr = 0; fr < 4; ++fr)
        #pragma unroll
        for (int rr = 0; rr < 4; ++rr) {
            const int row = q0 + wq * 64 + fr * 16 + (lane >> 4) * 4 + rr;
            const float linv = Li[b * 4096 + row];
            #pragma unroll
            for (int fc = 0; fc < 3; ++fc) {
                const int col = d0 + wd * 48 + fc * 16 + (lane & 15);
                out[((size_t)b * S + row) * D + col] = acc[fr][fc][rr] * linv;
            }
        }
}

extern "C" void kernel_launch(void* const* d_in, const int* in_sizes, int n_in,
                              void* d_out, int out_size, void* d_ws, size_t ws_size,
                              hipStream_t stream) {
    const float* x  = (const float*)d_in[0];
    const float* Wq = (const float*)d_in[1];
    const float* Wk = (const float*)d_in[2];
    const float* Wv = (const float*)d_in[3];
    float* out = (float*)d_out;

    const size_t SD = (size_t)16384 * 768;
    u16* q  = (u16*)d_ws;
    u16* k  = q  + SD;
    u16* vt = k  + SD;
    u16* xb = vt + SD;
    u16* WT = xb + SD;                         // 3*768*768
    u16* Pp = WT + (size_t)3 * 768 * 768;      // 4*528*16384 bf16 P tiles
    float* Lp = (float*)(Pp + (size_t)4 * 528 * 16384);   // 4*32*2*4096 f32
    float* Li = Lp + (size_t)4 * 32 * 2 * 4096;
    (void)in_sizes; (void)n_in; (void)out_size; (void)ws_size;

    conv_x  <<<12288, 256, 0, stream>>>(x, xb);
    conv_wt <<<dim3(12, 12, 3), 256, 0, stream>>>(Wq, Wk, Wv, WT);
    qkv_gemm<<<dim3(128, 6, 3), 256, 0, stream>>>(xb, WT, q, k, vt);
    qkt_gemm<<<dim3(528, 4), 256, 0, stream>>>(q, k, Pp, Lp);
    reduce_l<<<64, 256, 0, stream>>>(Lp, Li);
    pv_gemm <<<512, 512, 0, stream>>>(Pp, vt, Li, out);
}